// Round 1
// baseline (452.655 us; speedup 1.0000x reference)
//
#include <hip/hip_runtime.h>

// Problem constants (from reference)
#define BB 2
#define CC 3
#define HH 112
#define WW 112
#define NN (HH*WW)          // 12544 voxels
#define NPAIR (BB*CC)       // 6 (b,c) pairs
#define NCOMBO (NPAIR*2)    // 12 directed (pair, dir) combos
#define NBINS 24643         // max squared distance 111^2+111^2 = 24642

// ---------------------------------------------------------------------------
// Zero the accumulation region of the workspace (counts + qvals + histograms)
__global__ void zero_kernel(int* p, int n) {
    int i = blockIdx.x * blockDim.x + threadIdx.x;
    if (i < n) p[i] = 0;
}

// ---------------------------------------------------------------------------
// Fused: argmax over C (pred labels) + build compacted per-(b,class) point
// lists for both gt and seg masks. Coordinates packed as (i<<16)|j.
__global__ void build_kernel(const float* __restrict__ x,
                             const int* __restrict__ y,
                             int* gtCnt, int* segCnt,
                             int* gtList, int* segList) {
    int t = blockIdx.x * blockDim.x + threadIdx.x;
    if (t >= BB * NN) return;
    int b = t / NN, v = t % NN;

    // argmax over C=3 (strict > keeps first index, matching jnp.argmax)
    const float* xb = x + (size_t)b * CC * NN + v;
    float best = xb[0];
    int bi = 0;
#pragma unroll
    for (int c = 1; c < CC; c++) {
        float val = xb[(size_t)c * NN];
        if (val > best) { best = val; bi = c; }
    }

    int i = v / WW, j = v % WW;
    int packed = (i << 16) | j;

    int g = y[t];                         // gt label, guaranteed in [0,CC)
    int gi = atomicAdd(&gtCnt[b * CC + g], 1);
    gtList[(b * CC + g) * NN + gi] = packed;

    int si = atomicAdd(&segCnt[b * CC + bi], 1);
    segList[(b * CC + bi) * NN + si] = packed;
}

// ---------------------------------------------------------------------------
// For each directed combo z = pair*2+dir: every query point computes the min
// squared distance to the target point set (LDS-tiled), then bumps the
// histogram bin for that integer d2.
#define TILE 2048
__global__ void dist_kernel(const int* __restrict__ gtCnt,
                            const int* __restrict__ segCnt,
                            const int* __restrict__ gtList,
                            const int* __restrict__ segList,
                            int* __restrict__ hist) {
    int z = blockIdx.y;
    int dir = z & 1, pair = z >> 1;
    const int* qList; const int* tList; int nQ, nT;
    if (dir == 0) {  // hd1: queries = seg points, targets = gt points
        qList = segList + pair * NN; nQ = segCnt[pair];
        tList = gtList  + pair * NN; nT = gtCnt[pair];
    } else {         // hd2: queries = gt points, targets = seg points
        qList = gtList  + pair * NN; nQ = gtCnt[pair];
        tList = segList + pair * NN; nT = segCnt[pair];
    }
    if ((int)(blockIdx.x * blockDim.x) >= nQ || nT == 0) return;  // whole-block uniform exit

    __shared__ int sh[TILE];
    int qi = blockIdx.x * blockDim.x + threadIdx.x;
    bool active = (qi < nQ);
    int qx = 0, qy = 0;
    if (active) { int p = qList[qi]; qx = p >> 16; qy = p & 0xffff; }

    int mind = 0x7fffffff;
    for (int t0 = 0; t0 < nT; t0 += TILE) {
        int cnt = min(TILE, nT - t0);
        for (int k = threadIdx.x; k < cnt; k += blockDim.x) sh[k] = tList[t0 + k];
        __syncthreads();
        if (active) {
            for (int k = 0; k < cnt; k++) {
                int p  = sh[k];
                int dx = qx - (p >> 16);
                int dy = qy - (p & 0xffff);
                int d2 = dx * dx + dy * dy;
                mind = min(mind, d2);
            }
        }
        __syncthreads();
    }
    if (active) atomicAdd(&hist[z * NBINS + mind], 1);
}

// ---------------------------------------------------------------------------
// Per-combo exact quantile from the integer-d2 histogram.
// pos = 0.95*(n-1); ranks floor(pos), ceil(pos); linear interp in fp32
// (identical arithmetic to the reference's sorted-array indexing).
__global__ void quant_kernel(const int* __restrict__ gtCnt,
                             const int* __restrict__ segCnt,
                             const int* __restrict__ hist,
                             float* __restrict__ qval) {
    int z = blockIdx.x;
    int dir = z & 1, pair = z >> 1;
    int nQ = (dir == 0) ? segCnt[pair] : gtCnt[pair];
    int nT = (dir == 0) ? gtCnt[pair]  : segCnt[pair];
    if (nQ <= 0 || nT <= 0) { if (threadIdx.x == 0) qval[z] = 0.f; return; }

    const int* h = hist + z * NBINS;
    const int CHUNK = (NBINS + 255) / 256;  // 97 bins/thread
    int t = threadIdx.x;
    int lo = t * CHUNK, hiEnd = min(lo + CHUNK, NBINS);
    int s = 0;
    for (int i = lo; i < hiEnd; i++) s += h[i];

    __shared__ int scan[256];
    scan[t] = s;
    __syncthreads();
    for (int off = 1; off < 256; off <<= 1) {  // inclusive Hillis-Steele scan
        int v = scan[t];
        int add = (t >= off) ? scan[t - off] : 0;
        __syncthreads();
        scan[t] = v + add;
        __syncthreads();
    }

    float pos  = 0.95f * (float)(nQ - 1);
    int   klo  = (int)floorf(pos);
    int   khi  = (int)ceilf(pos);
    float frac = pos - (float)klo;

    __shared__ float vlh[2];
    int excl = scan[t] - s;  // exclusive prefix of this thread's chunk
    for (int which = 0; which < 2; which++) {
        int r = which ? khi : klo;
        if (r >= excl && r < scan[t]) {   // rank falls in my chunk
            int c = excl;
            for (int i = lo; i < hiEnd; i++) {
                c += h[i];
                if (c > r) { vlh[which] = sqrtf((float)i); break; }
            }
        }
        __syncthreads();
    }
    if (t == 0) qval[z] = vlh[0] * (1.f - frac) + vlh[1] * frac;
}

// ---------------------------------------------------------------------------
// Combine: hd(pair) = max(q1,q2) if both sets nonempty else 0; mean over 6.
__global__ void final_kernel(const int* __restrict__ gtCnt,
                             const int* __restrict__ segCnt,
                             const float* __restrict__ qval,
                             float* __restrict__ out) {
    if (threadIdx.x == 0 && blockIdx.x == 0) {
        float s = 0.f;
        for (int p = 0; p < NPAIR; p++) {
            float hd = 0.f;
            if (segCnt[p] > 0 && gtCnt[p] > 0)
                hd = fmaxf(qval[2 * p], qval[2 * p + 1]);
            s += hd;
        }
        out[0] = s / (float)NPAIR;
    }
}

// ---------------------------------------------------------------------------
extern "C" void kernel_launch(void* const* d_in, const int* in_sizes, int n_in,
                              void* d_out, int out_size, void* d_ws, size_t ws_size,
                              hipStream_t stream) {
    const float* x = (const float*)d_in[0];
    const int*   y = (const int*)d_in[1];
    float* out = (float*)d_out;

    // Workspace layout (4B units):
    int* ws      = (int*)d_ws;
    int* gtCnt   = ws;                         // NPAIR
    int* segCnt  = gtCnt + NPAIR;              // NPAIR
    float* qval  = (float*)(segCnt + NPAIR);   // NCOMBO
    int* hist    = (int*)(qval + NCOMBO);      // NCOMBO*NBINS
    int* gtList  = hist + NCOMBO * NBINS;      // NPAIR*NN
    int* segList = gtList + NPAIR * NN;        // NPAIR*NN
    // total ≈ 1.8 MB

    int zeroN = 2 * NPAIR + NCOMBO + NCOMBO * NBINS;
    zero_kernel<<<(zeroN + 255) / 256, 256, 0, stream>>>(gtCnt, zeroN);

    build_kernel<<<(BB * NN + 255) / 256, 256, 0, stream>>>(x, y, gtCnt, segCnt, gtList, segList);

    dim3 g((NN + 255) / 256, NCOMBO);
    dist_kernel<<<g, 256, 0, stream>>>(gtCnt, segCnt, gtList, segList, hist);

    quant_kernel<<<NCOMBO, 256, 0, stream>>>(gtCnt, segCnt, hist, qval);

    final_kernel<<<1, 64, 0, stream>>>(gtCnt, segCnt, qval, out);
}

// Round 2
// 74.787 us; speedup vs baseline: 6.0526x; 6.0526x over previous
//
#include <hip/hip_runtime.h>

// Problem constants (from reference)
#define BB 2
#define CC 3
#define HH 112
#define WW 112
#define NN (HH*WW)          // 12544 voxels
#define NPAIR (BB*CC)       // 6 (b,c) pairs
#define NCOMBO (NPAIR*2)    // 12 directed (pair, dir) combos
#define NBINS 24643         // max squared distance 111^2+111^2 = 24642
#define HWORDS ((NBINS + 1) / 2)   // packed 2 bins per int (counts < 2^16)
#define TT 1024             // targets per LDS tile in dist
#define TCHUNKS ((NN + TT - 1) / TT)   // 13
#define QBLOCKS ((NN + 255) / 256)     // 49

typedef short v2s __attribute__((ext_vector_type(2)));

// ---------------------------------------------------------------------------
// Init: zero the 12 counters, set minD to INT_MAX.
__global__ void init_kernel(int* __restrict__ cnts, int* __restrict__ minD) {
    int i = blockIdx.x * blockDim.x + threadIdx.x;
    if (i < 2 * NPAIR) cnts[i] = 0;
    if (i < NCOMBO * NN) minD[i] = 0x7fffffff;
}

// ---------------------------------------------------------------------------
// Fused argmax + compacted point-list build. Contention fix: per-class ballot
// -> per-wave popcount in LDS -> ONE atomicAdd per class per block (chain of
// 49 per counter address instead of ~4181 per-thread atomics).
__global__ __launch_bounds__(256) void build_kernel(
        const float* __restrict__ x, const int* __restrict__ y,
        int* __restrict__ gtCnt, int* __restrict__ segCnt,
        int* __restrict__ gtList, int* __restrict__ segList) {
    int t = blockIdx.x * 256 + threadIdx.x;          // grid exact: 98*256 = BB*NN
    int b = blockIdx.x / (NN / 256);                 // NN/256 = 49, so b is block-uniform
    int v = t - b * NN;

    // argmax over C=3 (strict > keeps first index, matching jnp.argmax)
    const float* xb = x + (size_t)b * CC * NN + v;
    float best = xb[0];
    int bi = 0;
#pragma unroll
    for (int c = 1; c < CC; c++) {
        float val = xb[(size_t)c * NN];
        if (val > best) { best = val; bi = c; }
    }

    int i = v / WW, j = v % WW;
    int packed = (i << 16) | j;
    int g = y[t];

    int lane = threadIdx.x & 63, wid = threadIdx.x >> 6;
    unsigned long long below = (lane == 63) ? 0xffffffffffffffffull >> 1
                                            : ((1ull << lane) - 1ull);

    __shared__ int wG[4][CC], wS[4][CC];
    __shared__ int baseG[CC], baseS[CC];

    unsigned long long mG0 = __ballot(g == 0), mG1 = __ballot(g == 1), mG2 = __ballot(g == 2);
    unsigned long long mS0 = __ballot(bi == 0), mS1 = __ballot(bi == 1), mS2 = __ballot(bi == 2);
    if (lane == 0) {
        wG[wid][0] = (int)__popcll(mG0); wG[wid][1] = (int)__popcll(mG1); wG[wid][2] = (int)__popcll(mG2);
        wS[wid][0] = (int)__popcll(mS0); wS[wid][1] = (int)__popcll(mS1); wS[wid][2] = (int)__popcll(mS2);
    }
    __syncthreads();
    if (threadIdx.x < CC) {
        int c = threadIdx.x;
        int tg = wG[0][c] + wG[1][c] + wG[2][c] + wG[3][c];
        int ts = wS[0][c] + wS[1][c] + wS[2][c] + wS[3][c];
        baseG[c] = atomicAdd(&gtCnt[b * CC + c], tg);
        baseS[c] = atomicAdd(&segCnt[b * CC + c], ts);
    }
    __syncthreads();

    // gt scatter
    unsigned long long myMG = (g == 0) ? mG0 : (g == 1) ? mG1 : mG2;
    int offG = baseG[g];
    for (int w = 0; w < wid; w++) offG += wG[w][g];
    offG += (int)__popcll(myMG & below);
    gtList[(b * CC + g) * NN + offG] = packed;

    // seg scatter
    unsigned long long myMS = (bi == 0) ? mS0 : (bi == 1) ? mS1 : mS2;
    int offS = baseS[bi];
    for (int w = 0; w < wid; w++) offS += wS[w][bi];
    offS += (int)__popcll(myMS & below);
    segList[(b * CC + bi) * NN + offS] = packed;
}

// ---------------------------------------------------------------------------
// Min-distance: grid (qBlocks, combo, tChunk). Each block stages TT targets in
// LDS, each thread keeps a partial min for its query, then atomicMin to the
// per-query global min (<=13-way contention per address).
__global__ __launch_bounds__(256) void dist_kernel(
        const int* __restrict__ gtCnt, const int* __restrict__ segCnt,
        const int* __restrict__ gtList, const int* __restrict__ segList,
        int* __restrict__ minD) {
    int z = blockIdx.y;
    int dir = z & 1, pair = z >> 1;
    const int* qList; const int* tList; int nQ, nT;
    if (dir == 0) {  // hd1: queries = seg, targets = gt
        qList = segList + pair * NN; nQ = segCnt[pair];
        tList = gtList  + pair * NN; nT = gtCnt[pair];
    } else {         // hd2: queries = gt, targets = seg
        qList = gtList  + pair * NN; nQ = gtCnt[pair];
        tList = segList + pair * NN; nT = segCnt[pair];
    }
    int t0 = blockIdx.z * TT;
    if ((int)(blockIdx.x * 256) >= nQ || t0 >= nT) return;  // block-uniform exit

    __shared__ int sh[TT];
    int cnt = min(TT, nT - t0);
    for (int k = threadIdx.x; k < cnt; k += 256) sh[k] = tList[t0 + k];
    __syncthreads();

    int qi = blockIdx.x * 256 + threadIdx.x;
    bool active = (qi < nQ);
    int qpk = active ? qList[qi] : 0;
    v2s qv = __builtin_bit_cast(v2s, qpk);

    int mind = 0x7fffffff;
    if (active) {
        int kk = 0;
        for (; kk + 4 <= cnt; kk += 4) {
            int4 p4 = *reinterpret_cast<const int4*>(&sh[kk]);  // ds_read_b128
#define DO_ONE(pp) { v2s d = qv - __builtin_bit_cast(v2s, (pp));                 \
        int d2;                                                                   \
        _Pragma("clang diagnostic push")                                          \
        d2 = 0;                                                                   \
        { int dx = d.x, dy = d.y; d2 = dx * dx + dy * dy; }                       \
        _Pragma("clang diagnostic pop")                                           \
        mind = min(mind, d2); }
            DO_ONE(p4.x) DO_ONE(p4.y) DO_ONE(p4.z) DO_ONE(p4.w)
        }
        for (; kk < cnt; kk++) DO_ONE(sh[kk])
#undef DO_ONE
        atomicMin(&minD[z * NN + qi], mind);
    }
}

// ---------------------------------------------------------------------------
// One block per combo: build a packed 16-bit LDS histogram of the integer min
// d2 values (hot bins stay LDS-local), then exact linear-interp quantile via
// block scan + rank search. Arithmetic identical to the reference.
__global__ __launch_bounds__(256) void quant_kernel(
        const int* __restrict__ gtCnt, const int* __restrict__ segCnt,
        const int* __restrict__ minD, float* __restrict__ qval) {
    int z = blockIdx.x;
    int dir = z & 1, pair = z >> 1;
    int nQ = (dir == 0) ? segCnt[pair] : gtCnt[pair];
    int nT = (dir == 0) ? gtCnt[pair]  : segCnt[pair];
    int tid = threadIdx.x;
    if (nQ <= 0 || nT <= 0) { if (tid == 0) qval[z] = 0.f; return; }

    __shared__ int h[HWORDS];            // 2 bins per int, counts < 2^16 so no carry
    __shared__ int pscan[256];
    __shared__ float vlh[2];

    for (int i = tid; i < HWORDS; i += 256) h[i] = 0;
    __syncthreads();
    for (int qi = tid; qi < nQ; qi += 256) {
        int d2 = minD[z * NN + qi];      // guaranteed < NBINS when nT > 0
        atomicAdd(&h[d2 >> 1], 1 << ((d2 & 1) << 4));
    }
    __syncthreads();

    const int CHUNK = (NBINS + 255) / 256;  // 97 bins/thread
    int lo = tid * CHUNK, hiEnd = min(lo + CHUNK, NBINS);
    int s = 0;
    for (int i = lo; i < hiEnd; i++) s += (h[i >> 1] >> ((i & 1) << 4)) & 0xffff;

    pscan[tid] = s;
    __syncthreads();
    for (int off = 1; off < 256; off <<= 1) {   // inclusive Hillis-Steele scan
        int v = pscan[tid];
        int add = (tid >= off) ? pscan[tid - off] : 0;
        __syncthreads();
        pscan[tid] = v + add;
        __syncthreads();
    }

    float pos  = 0.95f * (float)(nQ - 1);
    int   klo  = (int)floorf(pos);
    int   khi  = (int)ceilf(pos);
    float frac = pos - (float)klo;

    int excl = pscan[tid] - s;   // exclusive prefix of this thread's chunk
    for (int which = 0; which < 2; which++) {
        int r = which ? khi : klo;
        if (r >= excl && r < pscan[tid]) {   // rank falls in my chunk
            int c = excl;
            for (int i = lo; i < hiEnd; i++) {
                c += (h[i >> 1] >> ((i & 1) << 4)) & 0xffff;
                if (c > r) { vlh[which] = sqrtf((float)i); break; }
            }
        }
        __syncthreads();
    }
    if (tid == 0) qval[z] = vlh[0] * (1.f - frac) + vlh[1] * frac;
}

// ---------------------------------------------------------------------------
// Combine: hd(pair) = max(q1,q2) if both sets nonempty else 0; mean over 6.
__global__ void final_kernel(const int* __restrict__ gtCnt,
                             const int* __restrict__ segCnt,
                             const float* __restrict__ qval,
                             float* __restrict__ out) {
    if (threadIdx.x == 0 && blockIdx.x == 0) {
        float s = 0.f;
        for (int p = 0; p < NPAIR; p++) {
            float hd = 0.f;
            if (segCnt[p] > 0 && gtCnt[p] > 0)
                hd = fmaxf(qval[2 * p], qval[2 * p + 1]);
            s += hd;
        }
        out[0] = s / (float)NPAIR;
    }
}

// ---------------------------------------------------------------------------
extern "C" void kernel_launch(void* const* d_in, const int* in_sizes, int n_in,
                              void* d_out, int out_size, void* d_ws, size_t ws_size,
                              hipStream_t stream) {
    const float* x = (const float*)d_in[0];
    const int*   y = (const int*)d_in[1];
    float* out = (float*)d_out;

    // Workspace layout (4B units):
    int* ws      = (int*)d_ws;
    int* gtCnt   = ws;                         // NPAIR
    int* segCnt  = gtCnt + NPAIR;              // NPAIR   (contiguous with gtCnt)
    float* qval  = (float*)(segCnt + NPAIR);   // NCOMBO
    int* minD    = (int*)(qval + NCOMBO);      // NCOMBO*NN
    int* gtList  = minD + NCOMBO * NN;         // NPAIR*NN
    int* segList = gtList + NPAIR * NN;        // NPAIR*NN
    // total ~= 1.2 MB

    int initN = NCOMBO * NN;                   // covers counters too (first 12)
    init_kernel<<<(initN + 255) / 256, 256, 0, stream>>>(gtCnt, minD);

    build_kernel<<<(BB * NN) / 256, 256, 0, stream>>>(x, y, gtCnt, segCnt, gtList, segList);

    dim3 g(QBLOCKS, NCOMBO, TCHUNKS);
    dist_kernel<<<g, 256, 0, stream>>>(gtCnt, segCnt, gtList, segList, minD);

    quant_kernel<<<NCOMBO, 256, 0, stream>>>(gtCnt, segCnt, minD, qval);

    final_kernel<<<1, 64, 0, stream>>>(gtCnt, segCnt, qval, out);
}

// Round 3
// 51.310 us; speedup vs baseline: 8.8220x; 1.4576x over previous
//
#include <hip/hip_runtime.h>

// Problem constants (from reference)
#define BB 2
#define CC 3
#define HH 112
#define WW 112
#define NN (HH*WW)          // 12544 voxels
#define NPAIR (BB*CC)       // 6 (b,c) pairs
#define NCOMBO (NPAIR*2)    // 12 directed (pair, dir) combos
#define NBINS 24643         // max squared distance 111^2+111^2 = 24642
#define HWORDS ((NBINS + 1) / 2)   // packed 2 bins per int (counts < 2^16)
#define INF29 (1 << 29)

// ---------------------------------------------------------------------------
// Pred labels via argmax over C (strict >, first index wins — matches argmax).
__global__ __launch_bounds__(256) void label_kernel(
        const float* __restrict__ x, int* __restrict__ predL) {
    int t = blockIdx.x * 256 + threadIdx.x;     // grid exact: BB*NN/256 = 98
    int b = t / NN, v = t - b * NN;
    const float* xb = x + (size_t)b * CC * NN + v;
    float best = xb[0];
    int bi = 0;
#pragma unroll
    for (int c = 1; c < CC; c++) {
        float val = xb[(size_t)c * NN];
        if (val > best) { best = val; bi = c; }
    }
    predL[t] = bi;
}

// ---------------------------------------------------------------------------
// Vertical pass: for mask m = pair*2+src (src 0=gt labels y, 1=pred labels),
// G[m][y][x] = min over y' with lab[y'][x]==c of (y-y')^2  (INF29 if none).
// One block per (x, m); column labels staged in LDS.
__global__ __launch_bounds__(128) void vpass_kernel(
        const int* __restrict__ y, const int* __restrict__ predL,
        int* __restrict__ G) {
    int x = blockIdx.x;        // 0..WW-1
    int m = blockIdx.y;        // 0..11
    int pair = m >> 1, src = m & 1;
    int b = pair / CC, c = pair % CC;
    const int* lab = (src ? predL : y) + b * NN;

    __shared__ int col[HH];
    int tid = threadIdx.x;
    if (tid < HH) col[tid] = lab[tid * WW + x];
    __syncthreads();

    if (tid < HH) {
        int g = INF29;
        for (int yy = 0; yy < HH; yy++) {
            int dy = tid - yy;
            int d  = dy * dy;
            g = (col[yy] == c) ? min(g, d) : g;
        }
        G[m * NN + tid * WW + x] = g;
    }
}

// ---------------------------------------------------------------------------
// Horizontal pass: D[m][y][x] = min over x' of ((x-x')^2 + G[m][y][x']).
// This is the exact min squared Euclidean distance from (y,x) to mask m.
// One block per (y, m); G row staged in LDS (coalesced).
__global__ __launch_bounds__(128) void hpass_kernel(
        const int* __restrict__ G, int* __restrict__ D) {
    int yr = blockIdx.x;       // 0..HH-1
    int m  = blockIdx.y;       // 0..11
    int tid = threadIdx.x;

    __shared__ int row[WW];
    if (tid < WW) row[tid] = G[m * NN + yr * WW + tid];
    __syncthreads();

    if (tid < WW) {
        int d = INF29;
        for (int xx = 0; xx < WW; xx++) {
            int dx = tid - xx;
            d = min(d, dx * dx + row[xx]);
        }
        D[m * NN + yr * WW + tid] = d;
    }
}

// ---------------------------------------------------------------------------
// One block per combo z = pair*2+dir.
//   dir 0: queries = seg points (predL==c), distances to gt  -> D mask z (=pair*2+0)
//   dir 1: queries = gt  points (y==c),    distances to seg -> D mask z (=pair*2+1)
// Packed 16-bit LDS histogram of integer d2 over query points, then exact
// linear-interp 95th quantile via block scan + rank search. n = hist total.
__global__ __launch_bounds__(256) void quant_kernel(
        const int* __restrict__ y, const int* __restrict__ predL,
        const int* __restrict__ D, float* __restrict__ qval,
        int* __restrict__ qcnt) {
    int z = blockIdx.x;
    int dir = z & 1, pair = z >> 1;
    int b = pair / CC, c = pair % CC;
    const int* ql = (dir ? y : predL) + b * NN;   // query-side labels
    const int* Dz = D + z * NN;
    int tid = threadIdx.x;

    __shared__ int h[HWORDS];            // 2 bins per int, counts < 2^16
    __shared__ int pscan[256];
    __shared__ float vlh[2];

    for (int i = tid; i < HWORDS; i += 256) h[i] = 0;
    __syncthreads();
    for (int v = tid; v < NN; v += 256) {
        if (ql[v] == c) {
            int d2 = min(Dz[v], NBINS - 1);   // clamp only matters if target set empty (result unused then)
            atomicAdd(&h[d2 >> 1], 1 << ((d2 & 1) << 4));
        }
    }
    __syncthreads();

    const int CHUNK = (NBINS + 255) / 256;  // 97 bins/thread
    int lo = tid * CHUNK, hiEnd = min(lo + CHUNK, NBINS);
    int s = 0;
    for (int i = lo; i < hiEnd; i++) s += (h[i >> 1] >> ((i & 1) << 4)) & 0xffff;

    pscan[tid] = s;
    __syncthreads();
    for (int off = 1; off < 256; off <<= 1) {   // inclusive Hillis-Steele scan
        int v = pscan[tid];
        int add = (tid >= off) ? pscan[tid - off] : 0;
        __syncthreads();
        pscan[tid] = v + add;
        __syncthreads();
    }

    int n = pscan[255];                    // query-point count for this combo
    if (n == 0) { if (tid == 0) { qval[z] = 0.f; qcnt[z] = 0; } return; }

    float pos  = 0.95f * (float)(n - 1);
    int   klo  = (int)floorf(pos);
    int   khi  = (int)ceilf(pos);
    float frac = pos - (float)klo;

    int excl = pscan[tid] - s;   // exclusive prefix of this thread's chunk
    for (int which = 0; which < 2; which++) {
        int r = which ? khi : klo;
        if (r >= excl && r < pscan[tid]) {   // rank falls in my chunk
            int cacc = excl;
            for (int i = lo; i < hiEnd; i++) {
                cacc += (h[i >> 1] >> ((i & 1) << 4)) & 0xffff;
                if (cacc > r) { vlh[which] = sqrtf((float)i); break; }
            }
        }
        __syncthreads();
    }
    if (tid == 0) {
        qval[z] = vlh[0] * (1.f - frac) + vlh[1] * frac;
        qcnt[z] = n;
    }
}

// ---------------------------------------------------------------------------
// hd(pair) = max(q1,q2) if both point sets nonempty else 0; mean over 6 pairs.
// (qcnt[2p] = seg count, qcnt[2p+1] = gt count.)
__global__ void final_kernel(const float* __restrict__ qval,
                             const int* __restrict__ qcnt,
                             float* __restrict__ out) {
    if (threadIdx.x == 0 && blockIdx.x == 0) {
        float s = 0.f;
        for (int p = 0; p < NPAIR; p++) {
            float hd = 0.f;
            if (qcnt[2 * p] > 0 && qcnt[2 * p + 1] > 0)
                hd = fmaxf(qval[2 * p], qval[2 * p + 1]);
            s += hd;
        }
        out[0] = s / (float)NPAIR;
    }
}

// ---------------------------------------------------------------------------
extern "C" void kernel_launch(void* const* d_in, const int* in_sizes, int n_in,
                              void* d_out, int out_size, void* d_ws, size_t ws_size,
                              hipStream_t stream) {
    const float* x = (const float*)d_in[0];
    const int*   y = (const int*)d_in[1];
    float* out = (float*)d_out;

    // Workspace layout (4B units). Every word below is fully overwritten each
    // call (no init kernel, no global atomics needed).
    int*   ws    = (int*)d_ws;
    int*   predL = ws;                        // BB*NN
    int*   G     = predL + BB * NN;           // NCOMBO*NN
    int*   D     = G + NCOMBO * NN;           // NCOMBO*NN
    float* qval  = (float*)(D + NCOMBO * NN); // NCOMBO
    int*   qcnt  = (int*)(qval + NCOMBO);     // NCOMBO
    // total ~= 1.3 MB

    label_kernel<<<(BB * NN) / 256, 256, 0, stream>>>(x, predL);

    dim3 gv(WW, NCOMBO);
    vpass_kernel<<<gv, 128, 0, stream>>>(y, predL, G);

    dim3 gh(HH, NCOMBO);
    hpass_kernel<<<gh, 128, 0, stream>>>(G, D);

    quant_kernel<<<NCOMBO, 256, 0, stream>>>(y, predL, D, qval, qcnt);

    final_kernel<<<1, 64, 0, stream>>>(qval, qcnt, out);
}

// Round 4
// 36.866 us; speedup vs baseline: 12.2784x; 1.3918x over previous
//
#include <hip/hip_runtime.h>

// Problem constants (from reference)
#define BB 2
#define CC 3
#define HH 112
#define WW 112
#define NN (HH*WW)          // 12544 voxels
#define NPAIR (BB*CC)       // 6 (b,c) pairs
#define NCOMBO (NPAIR*2)    // 12 directed (pair, dir) combos
#define NBINS 24643         // max squared distance 111^2+111^2 = 24642
#define HWORDS ((NBINS + 1) / 2)   // packed 2 bins per int (counts < 2^16)
#define INF29 (1 << 29)
#define QTHREADS 512

// ---------------------------------------------------------------------------
// K1 — vertical pass, labels computed inline.
// Mask m = pair*2+src (src 0 = gt labels y, 1 = pred labels via argmax).
// G[m][y][x] = min over y' with lab[y'][x]==c of (y-y')^2  (INF29 if none).
// One block per (x, m). Block (0,0) also resets the `done` counter for K3.
__global__ __launch_bounds__(128) void vpass_kernel(
        const float* __restrict__ x, const int* __restrict__ yl,
        int* __restrict__ G, int* __restrict__ done) {
    int xc = blockIdx.x;       // 0..WW-1
    int m  = blockIdx.y;       // 0..11
    int pair = m >> 1, src = m & 1;
    int b = pair / CC, c = pair % CC;
    int tid = threadIdx.x;

    if (xc == 0 && m == 0 && tid == 0) *done = 0;

    __shared__ int colv[HH];   // 0 if label==c else INF29
    if (tid < HH) {
        int lab;
        if (src) {             // pred: argmax over C=3, strict > (first index wins)
            const float* xb = x + (size_t)b * CC * NN + (size_t)tid * WW + xc;
            float v0 = xb[0], v1 = xb[NN], v2 = xb[2 * (size_t)NN];
            float best = v0; lab = 0;
            if (v1 > best) { best = v1; lab = 1; }
            if (v2 > best) { lab = 2; }
        } else {
            lab = yl[b * NN + tid * WW + xc];
        }
        colv[tid] = (lab == c) ? 0 : INF29;
    }
    __syncthreads();

    if (tid < HH) {
        int g = INF29;
        for (int yy = 0; yy < HH; yy++) {
            int dy = tid - yy;
            g = min(g, dy * dy + colv[yy]);
        }
        G[m * NN + tid * WW + xc] = g;
    }
}

// ---------------------------------------------------------------------------
// K2 — horizontal pass: D[m][y][x] = min over x' of ((x-x')^2 + G[m][y][x']).
// Exact min squared Euclidean distance from (y,x) to mask m. One block per (y,m).
__global__ __launch_bounds__(128) void hpass_kernel(
        const int* __restrict__ G, int* __restrict__ D) {
    int yr = blockIdx.x;       // 0..HH-1
    int m  = blockIdx.y;       // 0..11
    int tid = threadIdx.x;

    __shared__ int row[WW];
    if (tid < WW) row[tid] = G[m * NN + yr * WW + tid];   // coalesced
    __syncthreads();

    if (tid < WW) {
        int d = INF29;
        for (int xx = 0; xx < WW; xx++) {
            int dx = tid - xx;
            d = min(d, dx * dx + row[xx]);
        }
        D[m * NN + yr * WW + tid] = d;                    // coalesced
    }
}

// ---------------------------------------------------------------------------
// K3 — per-combo histogram + exact linear-interp 95th quantile, with the
// classic threadfence/atomic-counter last-block finalize (deterministic:
// the final value is independent of block arrival order).
//   combo z = pair*2+dir; dir 0: queries = pred==c, D mask z (targets gt)
//                          dir 1: queries = gt==c,  D mask z (targets pred)
__global__ __launch_bounds__(QTHREADS) void quant_final_kernel(
        const float* __restrict__ x, const int* __restrict__ yl,
        const int* __restrict__ D, float* __restrict__ qvalg,
        int* __restrict__ qcntg, int* __restrict__ done,
        float* __restrict__ out) {
    int z = blockIdx.x;
    int dir = z & 1, pair = z >> 1;
    int b = pair / CC, c = pair % CC;
    const int* Dz = D + z * NN;
    int tid = threadIdx.x;

    __shared__ int h[HWORDS];          // packed 2 bins per int, counts < 2^16
    __shared__ int pscan[QTHREADS];
    __shared__ float vlh[2];
    __shared__ int lastFlag;
    __shared__ float rq[NCOMBO];
    __shared__ int   rc[NCOMBO];

    for (int i = tid; i < HWORDS; i += QTHREADS) h[i] = 0;
    __syncthreads();

    for (int v = tid; v < NN; v += QTHREADS) {
        int lab;
        if (dir) {
            lab = yl[b * NN + v];
        } else {                        // pred labels inline (coalesced loads)
            const float* xb = x + (size_t)b * CC * NN + v;
            float v0 = xb[0], v1 = xb[NN], v2 = xb[2 * (size_t)NN];
            float best = v0; lab = 0;
            if (v1 > best) { best = v1; lab = 1; }
            if (v2 > best) { lab = 2; }
        }
        if (lab == c) {
            int d2 = min(Dz[v], NBINS - 1);   // clamp only hit when target set empty (gated out later)
            atomicAdd(&h[d2 >> 1], 1 << ((d2 & 1) << 4));
        }
    }
    __syncthreads();

    const int CHUNK = (NBINS + QTHREADS - 1) / QTHREADS;  // 49 bins/thread
    int lo = tid * CHUNK, hiE = min(lo + CHUNK, NBINS);
    int s = 0;
    for (int i = lo; i < hiE; i++) s += (h[i >> 1] >> ((i & 1) << 4)) & 0xffff;

    pscan[tid] = s;
    __syncthreads();
    for (int off = 1; off < QTHREADS; off <<= 1) {   // inclusive Hillis-Steele scan
        int v = pscan[tid];
        int add = (tid >= off) ? pscan[tid - off] : 0;
        __syncthreads();
        pscan[tid] = v + add;
        __syncthreads();
    }

    int n = pscan[QTHREADS - 1];       // query-point count for this combo
    float qv = 0.f;
    if (n > 0) {
        float pos  = 0.95f * (float)(n - 1);
        int   klo  = (int)floorf(pos);
        int   khi  = (int)ceilf(pos);
        float frac = pos - (float)klo;

        int excl = pscan[tid] - s;     // exclusive prefix of this thread's chunk
        for (int which = 0; which < 2; which++) {
            int r = which ? khi : klo;
            if (r >= excl && r < pscan[tid]) {   // rank falls in my chunk
                int cacc = excl;
                for (int i = lo; i < hiE; i++) {
                    cacc += (h[i >> 1] >> ((i & 1) << 4)) & 0xffff;
                    if (cacc > r) { vlh[which] = sqrtf((float)i); break; }
                }
            }
            __syncthreads();
        }
        qv = vlh[0] * (1.f - frac) + vlh[1] * frac;
    }

    // Publish via device-scope atomics (cross-XCD safe), then last block finalizes.
    if (tid == 0) {
        atomicExch(&qvalg[z], qv);
        atomicExch(&qcntg[z], n);
        __threadfence();
        int prev = atomicAdd(done, 1);
        lastFlag = (prev == NCOMBO - 1);
    }
    __syncthreads();

    if (lastFlag) {
        __threadfence();
        if (tid < NCOMBO) {            // parallel device-scope coherent reads
            rq[tid] = atomicAdd(&qvalg[tid], 0.f);
            rc[tid] = atomicAdd(&qcntg[tid], 0);
        }
        __syncthreads();
        if (tid == 0) {
            float ssum = 0.f;
            for (int p = 0; p < NPAIR; p++) {
                float hd = 0.f;
                if (rc[2 * p] > 0 && rc[2 * p + 1] > 0)   // both point sets nonempty
                    hd = fmaxf(rq[2 * p], rq[2 * p + 1]);
                ssum += hd;
            }
            out[0] = ssum / (float)NPAIR;
        }
    }
}

// ---------------------------------------------------------------------------
extern "C" void kernel_launch(void* const* d_in, const int* in_sizes, int n_in,
                              void* d_out, int out_size, void* d_ws, size_t ws_size,
                              hipStream_t stream) {
    const float* x = (const float*)d_in[0];
    const int*   y = (const int*)d_in[1];
    float* out = (float*)d_out;

    // Workspace layout (4B units). Every word read is written earlier in the
    // same call (done reset by K1; G/D/qval/qcnt fully overwritten).
    int*   ws   = (int*)d_ws;
    int*   G    = ws;                          // NCOMBO*NN
    int*   D    = G + NCOMBO * NN;             // NCOMBO*NN
    float* qval = (float*)(D + NCOMBO * NN);   // NCOMBO
    int*   qcnt = (int*)(qval + NCOMBO);       // NCOMBO
    int*   done = qcnt + NCOMBO;               // 1
    // total ~= 1.2 MB

    dim3 gv(WW, NCOMBO);
    vpass_kernel<<<gv, 128, 0, stream>>>(x, y, G, done);

    dim3 gh(HH, NCOMBO);
    hpass_kernel<<<gh, 128, 0, stream>>>(G, D);

    quant_final_kernel<<<NCOMBO, QTHREADS, 0, stream>>>(x, y, D, qval, qcnt, done, out);
}